// Round 6
// baseline (377.260 us; speedup 1.0000x reference)
//
#include <hip/hip_runtime.h>

#define NNODES 50000
#define EDIM 64
#define WKLEN 9
#define NEDGE 800000
#define NPAD (NNODES + 64)

#define NBLK 12500    // 4 rows per 256-thread block (wave-per-row)

using bf16x8 = __attribute__((ext_vector_type(8))) __bf16;
using f32x4  = __attribute__((ext_vector_type(4))) float;

// ---- static device scratch ----
__device__ __align__(256) unsigned short g_xbf[NPAD * EDIM];     // bf16 x (padded)
__device__ __align__(256) unsigned short g_ABh[NNODES * 128];    // packed (cur1,t1)
__device__ __align__(256) unsigned short g_c1h[NPAD * EDIM];     // cur1 bf16 (nm0)
__device__ __align__(256) unsigned short g_c2h[NPAD * EDIM];     // cur2 bf16 (nm1)
__device__ __align__(256) unsigned short g_g0h[NNODES * EDIM];   // g0 then g1
__device__ __align__(256) unsigned short g_sc1h[NNODES * EDIM];  // s-branch c1
__device__ __align__(256) unsigned short g_Pr[NNODES * 128];     // x@W1top L0|L1
__device__ __align__(256) unsigned short g_Pc[NNODES * 128];     // x@W1bot L0|L1
__device__ __align__(256) float g_mt0[NEDGE];
__device__ __align__(256) float g_mt1[NEDGE];
__device__ __align__(256) float g_sm0[NNODES];
__device__ __align__(256) float g_sm1[NNODES];
__device__ __align__(256) int   g_rowptr[NNODES + 1];
__device__ __align__(256) unsigned short g_Tswz[2048 * 8];  // edge W1-half frags
__device__ __align__(256) unsigned short g_Sswz[1024 * 8];  // node-MLP W1 frags

__device__ __forceinline__ unsigned short f2bf(float f) {
    union { float f; unsigned int i; } v;
    v.f = f;
    unsigned int r = v.i + 0x7FFFu + ((v.i >> 16) & 1u);
    return (unsigned short)(r >> 16);
}
__device__ __forceinline__ float bf2f_lo(unsigned int u) {
    union { unsigned int i; float f; } v; v.i = u << 16; return v.f;
}
__device__ __forceinline__ float bf2f_hi(unsigned int u) {
    union { unsigned int i; float f; } v; v.i = u & 0xFFFF0000u; return v.f;
}

// ---------------------------------------------------------------------------
// L1: misc — x->bf16 | rowptr | W1-half swizzle (edge) | W1 swizzle (node)
// ---------------------------------------------------------------------------
__global__ __launch_bounds__(256) void misc_kernel(
    const float* __restrict__ x, const float* __restrict__ tW1,
    const float* __restrict__ sW1, const int* __restrict__ row,
    int n, int nE)
{
    int bid = blockIdx.x, tid = threadIdx.x;
    if (bid < 1563) {
        int i = bid * 256 + tid;
        if (i < NNODES * EDIM / 8) {
            const float* src = x + i * 8;
            union { unsigned short s[8]; uint4 q; } u;
#pragma unroll
            for (int j = 0; j < 8; ++j) u.s[j] = f2bf(src[j]);
            *(uint4*)&g_xbf[i * 8] = u.q;
        }
    } else if (bid < 1759) {
        int i = (bid - 1563) * 256 + tid;
        if (i > n) return;
        int lo = 0, hi = nE;
        while (lo < hi) {
            int mid = (lo + hi) >> 1;
            if (row[mid] < i) lo = mid + 1; else hi = mid;
        }
        g_rowptr[i] = lo;
    } else if (bid < 1767) {
        int t = (bid - 1759) * 256 + tid;   // 0..2047
        int s = t >> 9, f = (t >> 6) & 7, ln = t & 63;
        int li = s >> 1, half = s & 1, ks = f >> 2, nn = f & 3;
        int q = ln >> 4, mcl = ln & 15;
        union { unsigned short sv[8]; uint4 q4; } u;
#pragma unroll
        for (int j = 0; j < 8; ++j) {
            int kg = half * 64 + ks * 32 + q * 8 + j;
            u.sv[j] = f2bf(tW1[li * 8192 + kg * 64 + nn * 16 + mcl]);
        }
        *(uint4*)&g_Tswz[t * 8] = u.q4;
    } else {
        int t = (bid - 1767) * 256 + tid;  // 0..1023
        int li = t >> 9, ks = (t >> 8) & 1, nn = (t >> 6) & 3, ln = t & 63;
        int q = ln >> 4, mcl = ln & 15;
        union { unsigned short sv[8]; uint4 q4; } u;
#pragma unroll
        for (int j = 0; j < 8; ++j)
            u.sv[j] = f2bf(sW1[li * 4096 + (ks * 32 + q * 8 + j) * 64 + nn * 16 + mcl]);
        *(uint4*)&g_Sswz[t * 8] = u.q4;
    }
}

// ---------------------------------------------------------------------------
// L2a: prep2 — P = X @ W1_half for 4 sets via MFMA, bf16 packed out.
// ---------------------------------------------------------------------------
__global__ __launch_bounds__(256) void prep2_kernel(int n)
{
    int tid = threadIdx.x;
    int wave = tid >> 6, lane = tid & 63;
    int mc = lane & 15, quad = lane >> 4;
    int nb = blockIdx.x * 64 + wave * 16;
    const unsigned short* bp = g_xbf + (nb + mc) * 64 + quad * 8;
    bf16x8 af0 = *(const bf16x8*)bp;
    bf16x8 af1 = *(const bf16x8*)(bp + 32);
    const f32x4 zero = {0.f, 0.f, 0.f, 0.f};
#pragma unroll
    for (int s = 0; s < 4; ++s) {
        int li = s >> 1, half = s & 1;
        f32x4 acc[4];
#pragma unroll
        for (int nn = 0; nn < 4; ++nn) acc[nn] = zero;
#pragma unroll
        for (int nn = 0; nn < 4; ++nn) {
            bf16x8 b0 = *(const bf16x8*)&g_Tswz[((s * 8 + nn) * 64 + lane) * 8];
            bf16x8 b1 = *(const bf16x8*)&g_Tswz[((s * 8 + 4 + nn) * 64 + lane) * 8];
            acc[nn] = __builtin_amdgcn_mfma_f32_16x16x32_bf16(af0, b0, acc[nn], 0, 0, 0);
            acc[nn] = __builtin_amdgcn_mfma_f32_16x16x32_bf16(af1, b1, acc[nn], 0, 0, 0);
        }
        unsigned short* dst = half ? g_Pc : g_Pr;
#pragma unroll
        for (int nn = 0; nn < 4; ++nn)
#pragma unroll
            for (int r = 0; r < 4; ++r) {
                int node = nb + quad * 4 + r;
                if (node < n)
                    dst[node * 128 + li * 64 + nn * 16 + mc] = f2bf(acc[nn][r]);
            }
    }
}

// ---------------------------------------------------------------------------
// L2b: edge masks — wave = 8 edges x 8 lanes x 8 dims (R0 form).
// ---------------------------------------------------------------------------
__global__ __launch_bounds__(256) void edge_mask_kernel(
    const float* __restrict__ tb1, const float* __restrict__ tW2,
    const float* __restrict__ tb2, const float* __restrict__ tnoise,
    const int* __restrict__ row, const int* __restrict__ col,
    float* __restrict__ mask_out, int nE)
{
    int tid = threadIdx.x;
    int lane = tid & 63;
    int sub = lane & 7;
    int eg = lane >> 3;
    int wv = (blockIdx.x * 256 + tid) >> 6;
    int e = wv * 8 + eg;

    float b1_0[8], b1_1[8], w2_0[8], w2_1[8];
    *(float4*)&b1_0[0] = *(const float4*)&tb1[sub * 8];
    *(float4*)&b1_0[4] = *(const float4*)&tb1[sub * 8 + 4];
    *(float4*)&b1_1[0] = *(const float4*)&tb1[64 + sub * 8];
    *(float4*)&b1_1[4] = *(const float4*)&tb1[64 + sub * 8 + 4];
    *(float4*)&w2_0[0] = *(const float4*)&tW2[sub * 8];
    *(float4*)&w2_0[4] = *(const float4*)&tW2[sub * 8 + 4];
    *(float4*)&w2_1[0] = *(const float4*)&tW2[64 + sub * 8];
    *(float4*)&w2_1[4] = *(const float4*)&tW2[64 + sub * 8 + 4];

    int rn = row[e], cn = col[e];
    uint4 qr0 = *(const uint4*)&g_Pr[rn * 128 + sub * 8];
    uint4 qr1 = *(const uint4*)&g_Pr[rn * 128 + 64 + sub * 8];
    uint4 qc0 = *(const uint4*)&g_Pc[cn * 128 + sub * 8];
    uint4 qc1 = *(const uint4*)&g_Pc[cn * 128 + 64 + sub * 8];

    float p0 = 0.f, p1 = 0.f;
    unsigned r0[4] = {qr0.x, qr0.y, qr0.z, qr0.w};
    unsigned r1[4] = {qr1.x, qr1.y, qr1.z, qr1.w};
    unsigned c0[4] = {qc0.x, qc0.y, qc0.z, qc0.w};
    unsigned c1[4] = {qc1.x, qc1.y, qc1.z, qc1.w};
#pragma unroll
    for (int k = 0; k < 4; ++k) {
        float hA = fmaxf(bf2f_lo(r0[k]) + bf2f_lo(c0[k]) + b1_0[2 * k], 0.f);
        float hB = fmaxf(bf2f_hi(r0[k]) + bf2f_hi(c0[k]) + b1_0[2 * k + 1], 0.f);
        p0 = fmaf(hA, w2_0[2 * k], p0);
        p0 = fmaf(hB, w2_0[2 * k + 1], p0);
        float gA = fmaxf(bf2f_lo(r1[k]) + bf2f_lo(c1[k]) + b1_1[2 * k], 0.f);
        float gB = fmaxf(bf2f_hi(r1[k]) + bf2f_hi(c1[k]) + b1_1[2 * k + 1], 0.f);
        p1 = fmaf(gA, w2_1[2 * k], p1);
        p1 = fmaf(gB, w2_1[2 * k + 1], p1);
    }
#pragma unroll
    for (int off = 1; off <= 4; off <<= 1) {
        p0 += __shfl_xor(p0, off, 64);
        p1 += __shfl_xor(p1, off, 64);
    }
    if (sub == 0) {
        float z0 = (tnoise[e] + p0 + tb2[0]) * 2.0f;
        float m0 = 1.0f / (1.0f + expf(-z0));
        g_mt0[e] = m0;
        float z1 = (tnoise[nE + e] + p1 + tb2[1]) * 2.0f;
        float m1 = 1.0f / (1.0f + expf(-z1));
        g_mt1[e] = m1;
        mask_out[e] = m1;
    }
}

// ---------------------------------------------------------------------------
// node-MLP via MFMA: 16 nodes/wave
// ---------------------------------------------------------------------------
__device__ __forceinline__ void nm_body(
    int bid, const unsigned short* __restrict__ cur, int li,
    const float* __restrict__ b1, const float* __restrict__ W2,
    const float* __restrict__ b2, const float* __restrict__ noise,
    float* __restrict__ smout, int n)
{
    int tid = threadIdx.x;
    int wave = tid >> 6, lane = tid & 63;
    int mc = lane & 15, quad = lane >> 4;
    int nb = bid * 64 + wave * 16;
    const unsigned short* basep = cur + (nb + mc) * 64 + quad * 8;
    bf16x8 af0 = *(const bf16x8*)basep;
    bf16x8 af1 = *(const bf16x8*)(basep + 32);
    f32x4 acc[4];
    const f32x4 zero = {0.f, 0.f, 0.f, 0.f};
#pragma unroll
    for (int nn = 0; nn < 4; ++nn) acc[nn] = zero;
#pragma unroll
    for (int nn = 0; nn < 4; ++nn) {
        bf16x8 b0 = *(const bf16x8*)&g_Sswz[((li * 8 + nn) * 64 + lane) * 8];
        bf16x8 b1f = *(const bf16x8*)&g_Sswz[((li * 8 + 4 + nn) * 64 + lane) * 8];
        acc[nn] = __builtin_amdgcn_mfma_f32_16x16x32_bf16(af0, b0, acc[nn], 0, 0, 0);
        acc[nn] = __builtin_amdgcn_mfma_f32_16x16x32_bf16(af1, b1f, acc[nn], 0, 0, 0);
    }
    float p[4];
#pragma unroll
    for (int r = 0; r < 4; ++r) {
        float s = 0.f;
#pragma unroll
        for (int nn = 0; nn < 4; ++nn) {
            float h = acc[nn][r] + b1[nn * 16 + mc];
            s = fmaf(fmaxf(h, 0.f), W2[nn * 16 + mc], s);
        }
        p[r] = s;
    }
#pragma unroll
    for (int off = 8; off >= 1; off >>= 1)
#pragma unroll
        for (int r = 0; r < 4; ++r) p[r] += __shfl_xor(p[r], off, 64);
    if (mc == 0) {
        float b2v = b2[0];
#pragma unroll
        for (int r = 0; r < 4; ++r) {
            int node = nb + quad * 4 + r;
            if (node < n) {
                float z = (noise[node] + p[r] + b2v) * 2.0f;
                smout[node] = 1.0f / (1.0f + expf(-z));
            }
        }
    }
}

__global__ __launch_bounds__(256) void nm0_kernel(
    const float* __restrict__ sb1, const float* __restrict__ sW2,
    const float* __restrict__ sb2, const float* __restrict__ snz, int n)
{
    nm_body(blockIdx.x, g_c1h, 0, sb1, sW2, sb2, snz, g_sm0, n);
}

// ---------------------------------------------------------------------------
// L3: s1 — wave-per-row, 8 lanes/edge, uint4 gathers, no edge-path shfl.
// lane: eg = lane>>3 (edge in batch), sl = lane&7 (8 dims each).
// ---------------------------------------------------------------------------
__global__ __launch_bounds__(256) void s1_kernel(
    const int* __restrict__ colv, const float* __restrict__ vals, int n)
{
    int lane = threadIdx.x & 63;
    int eg = lane >> 3, sl = lane & 7;
    int w = blockIdx.x * 4 + (threadIdx.x >> 6);
    int s = g_rowptr[w], e = g_rowptr[w + 1];
    float ap[8], aq[8];
#pragma unroll
    for (int j = 0; j < 8; ++j) { ap[j] = 0.f; aq[j] = 0.f; }
    for (int base = s; base < e; base += 32) {
        int ci[4]; float vi[4], mi[4];
#pragma unroll
        for (int j = 0; j < 4; ++j) {
            int idx = base + j * 8 + eg;
            bool ok = idx < e;
            ci[j] = ok ? colv[idx] : 0;
            float v = ok ? vals[idx] : 0.f;
            vi[j] = v;
            mi[j] = ok ? v * g_mt0[idx] : 0.f;
        }
        uint4 uu[4];
#pragma unroll
        for (int j = 0; j < 4; ++j)
            uu[j] = *(const uint4*)&g_xbf[ci[j] * 64 + sl * 8];
#pragma unroll
        for (int j = 0; j < 4; ++j) {
            float f0 = bf2f_lo(uu[j].x), f1 = bf2f_hi(uu[j].x);
            float f2 = bf2f_lo(uu[j].y), f3 = bf2f_hi(uu[j].y);
            float f4 = bf2f_lo(uu[j].z), f5 = bf2f_hi(uu[j].z);
            float f6 = bf2f_lo(uu[j].w), f7 = bf2f_hi(uu[j].w);
            ap[0] = fmaf(vi[j], f0, ap[0]); aq[0] = fmaf(mi[j], f0, aq[0]);
            ap[1] = fmaf(vi[j], f1, ap[1]); aq[1] = fmaf(mi[j], f1, aq[1]);
            ap[2] = fmaf(vi[j], f2, ap[2]); aq[2] = fmaf(mi[j], f2, aq[2]);
            ap[3] = fmaf(vi[j], f3, ap[3]); aq[3] = fmaf(mi[j], f3, aq[3]);
            ap[4] = fmaf(vi[j], f4, ap[4]); aq[4] = fmaf(mi[j], f4, aq[4]);
            ap[5] = fmaf(vi[j], f5, ap[5]); aq[5] = fmaf(mi[j], f5, aq[5]);
            ap[6] = fmaf(vi[j], f6, ap[6]); aq[6] = fmaf(mi[j], f6, aq[6]);
            ap[7] = fmaf(vi[j], f7, ap[7]); aq[7] = fmaf(mi[j], f7, aq[7]);
        }
    }
#pragma unroll
    for (int m = 8; m <= 32; m <<= 1)
#pragma unroll
        for (int j = 0; j < 8; ++j) {
            ap[j] += __shfl_xor(ap[j], m, 64);
            aq[j] += __shfl_xor(aq[j], m, 64);
        }
    if (eg == 0) {
        uint4 A, B;
        A.x = (unsigned)f2bf(ap[0]) | ((unsigned)f2bf(aq[0]) << 16);
        A.y = (unsigned)f2bf(ap[1]) | ((unsigned)f2bf(aq[1]) << 16);
        A.z = (unsigned)f2bf(ap[2]) | ((unsigned)f2bf(aq[2]) << 16);
        A.w = (unsigned)f2bf(ap[3]) | ((unsigned)f2bf(aq[3]) << 16);
        B.x = (unsigned)f2bf(ap[4]) | ((unsigned)f2bf(aq[4]) << 16);
        B.y = (unsigned)f2bf(ap[5]) | ((unsigned)f2bf(aq[5]) << 16);
        B.z = (unsigned)f2bf(ap[6]) | ((unsigned)f2bf(aq[6]) << 16);
        B.w = (unsigned)f2bf(ap[7]) | ((unsigned)f2bf(aq[7]) << 16);
        *(uint4*)&g_ABh[w * 128 + 16 * sl] = A;
        *(uint4*)&g_ABh[w * 128 + 16 * sl + 8] = B;
        uint4 C;
        C.x = (unsigned)f2bf(ap[0]) | ((unsigned)f2bf(ap[1]) << 16);
        C.y = (unsigned)f2bf(ap[2]) | ((unsigned)f2bf(ap[3]) << 16);
        C.z = (unsigned)f2bf(ap[4]) | ((unsigned)f2bf(ap[5]) << 16);
        C.w = (unsigned)f2bf(ap[6]) | ((unsigned)f2bf(ap[7]) << 16);
        *(uint4*)&g_c1h[w * 64 + 8 * sl] = C;
    }
}

// ---------------------------------------------------------------------------
// rw gate body — wave-per-row, 8 lanes/edge (9th edge weight on eg==0 only).
// ---------------------------------------------------------------------------
__device__ __forceinline__ void rw_body(
    int w, const int* __restrict__ rw_col, const float* __restrict__ rwv,
    const unsigned short* __restrict__ cur, const float* __restrict__ smask,
    unsigned short* __restrict__ outg)
{
    int lane = threadIdx.x & 63;
    int eg = lane >> 3, sl = lane & 7;
    int base = w * WKLEN;
    int c1 = rw_col[base + eg];
    float v1 = rwv[base + eg];
    int c9 = rw_col[base + 8];
    float v9 = (eg == 0) ? rwv[base + 8] : 0.f;
    uint4 u1 = *(const uint4*)&cur[c1 * 64 + sl * 8];
    uint4 u9 = *(const uint4*)&cur[c9 * 64 + sl * 8];
    uint4 us = *(const uint4*)&cur[w * 64 + sl * 8];
    float a[8];
    a[0] = v1 * bf2f_lo(u1.x) + v9 * bf2f_lo(u9.x);
    a[1] = v1 * bf2f_hi(u1.x) + v9 * bf2f_hi(u9.x);
    a[2] = v1 * bf2f_lo(u1.y) + v9 * bf2f_lo(u9.y);
    a[3] = v1 * bf2f_hi(u1.y) + v9 * bf2f_hi(u9.y);
    a[4] = v1 * bf2f_lo(u1.z) + v9 * bf2f_lo(u9.z);
    a[5] = v1 * bf2f_hi(u1.z) + v9 * bf2f_hi(u9.z);
    a[6] = v1 * bf2f_lo(u1.w) + v9 * bf2f_lo(u9.w);
    a[7] = v1 * bf2f_hi(u1.w) + v9 * bf2f_hi(u9.w);
#pragma unroll
    for (int m = 8; m <= 32; m <<= 1)
#pragma unroll
        for (int j = 0; j < 8; ++j) a[j] += __shfl_xor(a[j], m, 64);
    float sm = smask[w];
    float sf[8] = { bf2f_lo(us.x), bf2f_hi(us.x), bf2f_lo(us.y), bf2f_hi(us.y),
                    bf2f_lo(us.z), bf2f_hi(us.z), bf2f_lo(us.w), bf2f_hi(us.w) };
    float r[8];
#pragma unroll
    for (int j = 0; j < 8; ++j) r[j] = sm * sf[j] + (1.f - sm) * a[j];
    if (eg == 0) {
        uint4 O;
        O.x = (unsigned)f2bf(r[0]) | ((unsigned)f2bf(r[1]) << 16);
        O.y = (unsigned)f2bf(r[2]) | ((unsigned)f2bf(r[3]) << 16);
        O.z = (unsigned)f2bf(r[4]) | ((unsigned)f2bf(r[5]) << 16);
        O.w = (unsigned)f2bf(r[6]) | ((unsigned)f2bf(r[7]) << 16);
        *(uint4*)&outg[w * 64 + 8 * sl] = O;
    }
}

// ---------------------------------------------------------------------------
// L5: s2 (emb_t, c2h) || rw0 (g0) — wave-per-row; s2: 16 lanes/edge (256B rows)
// ---------------------------------------------------------------------------
__global__ __launch_bounds__(256) void s2_rw0_kernel(
    const int* __restrict__ colv, const float* __restrict__ vals,
    const int* __restrict__ rw_col, const float* __restrict__ rwv,
    const float* __restrict__ x, float* __restrict__ emb_t, int n)
{
    int lane = threadIdx.x & 63;
    if (blockIdx.x >= NBLK) {
        int w = (blockIdx.x - NBLK) * 4 + (threadIdx.x >> 6);
        rw_body(w, rw_col, rwv, g_xbf, g_sm0, g_g0h);
        return;
    }
    int eg = lane >> 4, sl = lane & 15;
    int w = blockIdx.x * 4 + (threadIdx.x >> 6);
    int s = g_rowptr[w], e = g_rowptr[w + 1];
    float ac[4], at[4];
#pragma unroll
    for (int j = 0; j < 4; ++j) { ac[j] = 0.f; at[j] = 0.f; }
    for (int base = s; base < e; base += 16) {
        int ci[4]; float vi[4], mi[4];
#pragma unroll
        for (int j = 0; j < 4; ++j) {
            int idx = base + j * 4 + eg;
            bool ok = idx < e;
            ci[j] = ok ? colv[idx] : 0;
            float v = ok ? vals[idx] : 0.f;
            vi[j] = v;
            mi[j] = ok ? v * g_mt1[idx] : 0.f;
        }
        uint4 uu[4];
#pragma unroll
        for (int j = 0; j < 4; ++j)
            uu[j] = *(const uint4*)&g_ABh[ci[j] * 128 + sl * 8];
#pragma unroll
        for (int j = 0; j < 4; ++j) {
            ac[0] = fmaf(vi[j], bf2f_lo(uu[j].x), ac[0]);
            at[0] = fmaf(mi[j], bf2f_hi(uu[j].x), at[0]);
            ac[1] = fmaf(vi[j], bf2f_lo(uu[j].y), ac[1]);
            at[1] = fmaf(mi[j], bf2f_hi(uu[j].y), at[1]);
            ac[2] = fmaf(vi[j], bf2f_lo(uu[j].z), ac[2]);
            at[2] = fmaf(mi[j], bf2f_hi(uu[j].z), at[2]);
            ac[3] = fmaf(vi[j], bf2f_lo(uu[j].w), ac[3]);
            at[3] = fmaf(mi[j], bf2f_hi(uu[j].w), at[3]);
        }
    }
#pragma unroll
    for (int m = 16; m <= 32; m <<= 1)
#pragma unroll
        for (int j = 0; j < 4; ++j) {
            ac[j] += __shfl_xor(ac[j], m, 64);
            at[j] += __shfl_xor(at[j], m, 64);
        }
    if (eg == 0) {
        int o = w * 64 + 4 * sl;
        uint4 Uv = *(const uint4*)&g_ABh[w * 128 + sl * 8];
        float4 xv = *(const float4*)&x[o];
        float4 et;
        et.x = (xv.x + bf2f_hi(Uv.x) + at[0]) * (1.0f / 3.0f);
        et.y = (xv.y + bf2f_hi(Uv.y) + at[1]) * (1.0f / 3.0f);
        et.z = (xv.z + bf2f_hi(Uv.z) + at[2]) * (1.0f / 3.0f);
        et.w = (xv.w + bf2f_hi(Uv.w) + at[3]) * (1.0f / 3.0f);
        *(float4*)&emb_t[o] = et;
        uint2 ch;
        ch.x = (unsigned)f2bf(ac[0]) | ((unsigned)f2bf(ac[1]) << 16);
        ch.y = (unsigned)f2bf(ac[2]) | ((unsigned)f2bf(ac[3]) << 16);
        *(uint2*)&g_c2h[o] = ch;
    }
}

// ---------------------------------------------------------------------------
// generic spmm wave body: 128B bf16 rows, 8 lanes/edge
// ---------------------------------------------------------------------------
__device__ __forceinline__ void spmm_row_wave(
    int w, const int* __restrict__ colv, const float* __restrict__ vals,
    const unsigned short* __restrict__ h, float acc[8], int eg, int sl)
{
    int s = g_rowptr[w], e = g_rowptr[w + 1];
#pragma unroll
    for (int j = 0; j < 8; ++j) acc[j] = 0.f;
    for (int base = s; base < e; base += 32) {
        int ci[4]; float vi[4];
#pragma unroll
        for (int j = 0; j < 4; ++j) {
            int idx = base + j * 8 + eg;
            bool ok = idx < e;
            ci[j] = ok ? colv[idx] : 0;
            vi[j] = ok ? vals[idx] : 0.f;
        }
        uint4 uu[4];
#pragma unroll
        for (int j = 0; j < 4; ++j)
            uu[j] = *(const uint4*)&h[ci[j] * 64 + sl * 8];
#pragma unroll
        for (int j = 0; j < 4; ++j) {
            acc[0] = fmaf(vi[j], bf2f_lo(uu[j].x), acc[0]);
            acc[1] = fmaf(vi[j], bf2f_hi(uu[j].x), acc[1]);
            acc[2] = fmaf(vi[j], bf2f_lo(uu[j].y), acc[2]);
            acc[3] = fmaf(vi[j], bf2f_hi(uu[j].y), acc[3]);
            acc[4] = fmaf(vi[j], bf2f_lo(uu[j].z), acc[4]);
            acc[5] = fmaf(vi[j], bf2f_hi(uu[j].z), acc[5]);
            acc[6] = fmaf(vi[j], bf2f_lo(uu[j].w), acc[6]);
            acc[7] = fmaf(vi[j], bf2f_hi(uu[j].w), acc[7]);
        }
    }
#pragma unroll
    for (int m = 8; m <= 32; m <<= 1)
#pragma unroll
        for (int j = 0; j < 8; ++j) acc[j] += __shfl_xor(acc[j], m, 64);
}

// ---------------------------------------------------------------------------
// L6: spmm10 (sc1 = A·g0) || nm1 (sm1 from c2h)
// ---------------------------------------------------------------------------
__global__ __launch_bounds__(256) void spmm10_nm1_kernel(
    const int* __restrict__ colv, const float* __restrict__ vals,
    const float* __restrict__ sb1, const float* __restrict__ sW2,
    const float* __restrict__ sb2, const float* __restrict__ snz, int n)
{
    if (blockIdx.x >= NBLK) {
        nm_body(blockIdx.x - NBLK, g_c2h, 1, sb1, sW2, sb2, snz, g_sm1, n);
        return;
    }
    int lane = threadIdx.x & 63;
    int eg = lane >> 3, sl = lane & 7;
    int w = blockIdx.x * 4 + (threadIdx.x >> 6);
    float a[8];
    spmm_row_wave(w, colv, vals, g_g0h, a, eg, sl);
    if (eg == 0) {
        uint4 O;
        O.x = (unsigned)f2bf(a[0]) | ((unsigned)f2bf(a[1]) << 16);
        O.y = (unsigned)f2bf(a[2]) | ((unsigned)f2bf(a[3]) << 16);
        O.z = (unsigned)f2bf(a[4]) | ((unsigned)f2bf(a[5]) << 16);
        O.w = (unsigned)f2bf(a[6]) | ((unsigned)f2bf(a[7]) << 16);
        *(uint4*)&g_sc1h[w * 64 + 8 * sl] = O;
    }
}

// ---------------------------------------------------------------------------
// L7: g1 = rwgate(c1)
// ---------------------------------------------------------------------------
__global__ __launch_bounds__(256) void rw1_kernel(
    const int* __restrict__ rw_col, const float* __restrict__ rwv)
{
    int w = blockIdx.x * 4 + (threadIdx.x >> 6);
    rw_body(w, rw_col, rwv, g_sc1h, g_sm1, g_g0h);
}

// ---------------------------------------------------------------------------
// L8: emb_s = (x + c1 + spmm(vals, g1))/3, merged with finalize
// ---------------------------------------------------------------------------
__global__ __launch_bounds__(256) void spmm12_fin_kernel(
    const int* __restrict__ colv, const float* __restrict__ vals,
    const float* __restrict__ x, float* __restrict__ emb_s,
    float* __restrict__ out, int n)
{
    if (blockIdx.x >= NBLK) {
        __shared__ float red[256];
        float s = 0.f;
        for (int i = threadIdx.x; i < n; i += 256) s += g_sm0[i] + g_sm1[i];
        red[threadIdx.x] = s;
        __syncthreads();
        for (int off = 128; off >= 1; off >>= 1) {
            if (threadIdx.x < off) red[threadIdx.x] += red[threadIdx.x + off];
            __syncthreads();
        }
        if (threadIdx.x == 0) {
            out[6400000] = 0.0f;
            out[6400001] = red[0] / (2.0f * n);
        }
        return;
    }
    int lane = threadIdx.x & 63;
    int eg = lane >> 3, sl = lane & 7;
    int w = blockIdx.x * 4 + (threadIdx.x >> 6);
    float a[8];
    spmm_row_wave(w, colv, vals, g_g0h, a, eg, sl);
    if (eg == 0) {
        int o = w * 64 + 8 * sl;
        uint4 uc = *(const uint4*)&g_sc1h[o];
        float4 xa = *(const float4*)&x[o];
        float4 xb = *(const float4*)&x[o + 4];
        float4 ea, eb;
        ea.x = (xa.x + bf2f_lo(uc.x) + a[0]) * (1.0f / 3.0f);
        ea.y = (xa.y + bf2f_hi(uc.x) + a[1]) * (1.0f / 3.0f);
        ea.z = (xa.z + bf2f_lo(uc.y) + a[2]) * (1.0f / 3.0f);
        ea.w = (xa.w + bf2f_hi(uc.y) + a[3]) * (1.0f / 3.0f);
        eb.x = (xb.x + bf2f_lo(uc.z) + a[4]) * (1.0f / 3.0f);
        eb.y = (xb.y + bf2f_hi(uc.z) + a[5]) * (1.0f / 3.0f);
        eb.z = (xb.z + bf2f_lo(uc.w) + a[6]) * (1.0f / 3.0f);
        eb.w = (xb.w + bf2f_hi(uc.w) + a[7]) * (1.0f / 3.0f);
        *(float4*)&emb_s[o] = ea;
        *(float4*)&emb_s[o + 4] = eb;
    }
}

extern "C" void kernel_launch(void* const* d_in, const int* in_sizes, int n_in,
                              void* d_out, int out_size, void* d_ws, size_t ws_size,
                              hipStream_t stream)
{
    const float* x    = (const float*)d_in[0];
    const float* vals = (const float*)d_in[1];
    const float* rwv  = (const float*)d_in[2];
    const float* tW1  = (const float*)d_in[3];
    const float* tb1  = (const float*)d_in[4];
    const float* tW2  = (const float*)d_in[5];
    const float* tb2  = (const float*)d_in[6];
    const float* sW1  = (const float*)d_in[7];
    const float* sb1  = (const float*)d_in[8];
    const float* sW2  = (const float*)d_in[9];
    const float* sb2  = (const float*)d_in[10];
    const float* tnz  = (const float*)d_in[11];
    const float* snz  = (const float*)d_in[12];
    const int* row   = (const int*)d_in[13];
    const int* colv  = (const int*)d_in[14];
    const int* rwcol = (const int*)d_in[16];

    const int n = NNODES;
    const int nE = in_sizes[1];

    float* out   = (float*)d_out;
    float* emb_t = out;
    float* emb_s = out + 3200000;
    float* masko = out + 6400002;

    // L1: misc prep
    misc_kernel<<<1771, 256, 0, stream>>>(x, tW1, sW1, row, n, nE);
    // L2a: P = X @ W1_halves
    prep2_kernel<<<782, 256, 0, stream>>>(n);
    // L2b: edge masks
    edge_mask_kernel<<<nE / 32, 256, 0, stream>>>(tb1, tW2, tb2, tnz,
                                                  row, colv, masko, nE);
    // L3: s1 (cur1|t1 packed + cur1h)
    s1_kernel<<<NBLK, 256, 0, stream>>>(colv, vals, n);
    // L4: nm0 -> sm0
    nm0_kernel<<<782, 256, 0, stream>>>(sb1, sW2, sb2, snz, n);
    // L5: s2 || rw0
    s2_rw0_kernel<<<2 * NBLK, 256, 0, stream>>>(colv, vals, rwcol, rwv, x, emb_t, n);
    // L6: spmm10 || nm1
    spmm10_nm1_kernel<<<NBLK + 782, 256, 0, stream>>>(colv, vals,
                                                      sb1 + 64, sW2 + 64, sb2 + 1,
                                                      snz + n, n);
    // L7: g1 = rwgate(c1)
    rw1_kernel<<<NBLK, 256, 0, stream>>>(rwcol, rwv);
    // L8: emb_s + scalars
    spmm12_fin_kernel<<<NBLK + 1, 256, 0, stream>>>(colv, vals, x, emb_s, out, n);
}

// Round 7
// 328.461 us; speedup vs baseline: 1.1486x; 1.1486x over previous
//
#include <hip/hip_runtime.h>

#define NNODES 50000
#define EDIM 64
#define WKLEN 9
#define NEDGE 800000
#define NPAD (NNODES + 64)

#define NGRP 6250      // row groups of 8 rows
#define FINGS 1250     // persistent grid for fin kernel only

using bf16x8 = __attribute__((ext_vector_type(8))) __bf16;
using f32x4  = __attribute__((ext_vector_type(4))) float;

// ---- static device scratch ----
__device__ __align__(256) unsigned short g_xbf[NPAD * EDIM];     // bf16 x (padded)
__device__ __align__(256) unsigned short g_ABh[NNODES * 128];    // packed (cur1,t1)
__device__ __align__(256) unsigned short g_c1h[NPAD * EDIM];     // cur1 bf16 (nm0)
__device__ __align__(256) unsigned short g_c2h[NPAD * EDIM];     // cur2 bf16 (nm1)
__device__ __align__(256) unsigned short g_g0h[NNODES * EDIM];   // g0 then g1
__device__ __align__(256) unsigned short g_sc1h[NNODES * EDIM];  // s-branch c1
__device__ __align__(256) unsigned short g_Pr[NNODES * 128];     // x@W1top L0|L1
__device__ __align__(256) unsigned short g_Pc[NNODES * 128];     // x@W1bot L0|L1
__device__ __align__(256) float g_mt0[NEDGE];
__device__ __align__(256) float g_mt1[NEDGE];
__device__ __align__(256) float g_sm0[NNODES];
__device__ __align__(256) float g_sm1[NNODES];
__device__ __align__(256) int   g_rowptr[NNODES + 1];
__device__ __align__(256) unsigned short g_Tswz[2048 * 8];  // edge W1-half frags
__device__ __align__(256) unsigned short g_Sswz[1024 * 8];  // node-MLP W1 frags

__device__ __forceinline__ unsigned short f2bf(float f) {
    union { float f; unsigned int i; } v;
    v.f = f;
    unsigned int r = v.i + 0x7FFFu + ((v.i >> 16) & 1u);
    return (unsigned short)(r >> 16);
}
__device__ __forceinline__ float bf2f_lo(unsigned int u) {
    union { unsigned int i; float f; } v; v.i = u << 16; return v.f;
}
__device__ __forceinline__ float bf2f_hi(unsigned int u) {
    union { unsigned int i; float f; } v; v.i = u & 0xFFFF0000u; return v.f;
}

// ---------------------------------------------------------------------------
// L1: misc — x->bf16 | rowptr | W1-half swizzle (edge) | W1 swizzle (node)
// ---------------------------------------------------------------------------
__global__ __launch_bounds__(256) void misc_kernel(
    const float* __restrict__ x, const float* __restrict__ tW1,
    const float* __restrict__ sW1, const int* __restrict__ row,
    int n, int nE)
{
    int bid = blockIdx.x, tid = threadIdx.x;
    if (bid < 1563) {
        int i = bid * 256 + tid;
        if (i < NNODES * EDIM / 8) {
            const float* src = x + i * 8;
            union { unsigned short s[8]; uint4 q; } u;
#pragma unroll
            for (int j = 0; j < 8; ++j) u.s[j] = f2bf(src[j]);
            *(uint4*)&g_xbf[i * 8] = u.q;
        }
    } else if (bid < 1759) {
        int i = (bid - 1563) * 256 + tid;
        if (i > n) return;
        int lo = 0, hi = nE;
        while (lo < hi) {
            int mid = (lo + hi) >> 1;
            if (row[mid] < i) lo = mid + 1; else hi = mid;
        }
        g_rowptr[i] = lo;
    } else if (bid < 1767) {
        int t = (bid - 1759) * 256 + tid;   // 0..2047
        int s = t >> 9, f = (t >> 6) & 7, ln = t & 63;
        int li = s >> 1, half = s & 1, ks = f >> 2, nn = f & 3;
        int q = ln >> 4, mcl = ln & 15;
        union { unsigned short sv[8]; uint4 q4; } u;
#pragma unroll
        for (int j = 0; j < 8; ++j) {
            int kg = half * 64 + ks * 32 + q * 8 + j;
            u.sv[j] = f2bf(tW1[li * 8192 + kg * 64 + nn * 16 + mcl]);
        }
        *(uint4*)&g_Tswz[t * 8] = u.q4;
    } else {
        int t = (bid - 1767) * 256 + tid;  // 0..1023
        int li = t >> 9, ks = (t >> 8) & 1, nn = (t >> 6) & 3, ln = t & 63;
        int q = ln >> 4, mcl = ln & 15;
        union { unsigned short sv[8]; uint4 q4; } u;
#pragma unroll
        for (int j = 0; j < 8; ++j)
            u.sv[j] = f2bf(sW1[li * 4096 + (ks * 32 + q * 8 + j) * 64 + nn * 16 + mcl]);
        *(uint4*)&g_Sswz[t * 8] = u.q4;
    }
}

// ---------------------------------------------------------------------------
// L2a: prep2 — P = X @ W1_half for 4 sets via MFMA, bf16 packed out.
// ---------------------------------------------------------------------------
__global__ __launch_bounds__(256) void prep2_kernel(int n)
{
    int tid = threadIdx.x;
    int wave = tid >> 6, lane = tid & 63;
    int mc = lane & 15, quad = lane >> 4;
    int nb = blockIdx.x * 64 + wave * 16;
    const unsigned short* bp = g_xbf + (nb + mc) * 64 + quad * 8;
    bf16x8 af0 = *(const bf16x8*)bp;
    bf16x8 af1 = *(const bf16x8*)(bp + 32);
    const f32x4 zero = {0.f, 0.f, 0.f, 0.f};
#pragma unroll
    for (int s = 0; s < 4; ++s) {
        int li = s >> 1, half = s & 1;
        f32x4 acc[4];
#pragma unroll
        for (int nn = 0; nn < 4; ++nn) acc[nn] = zero;
#pragma unroll
        for (int nn = 0; nn < 4; ++nn) {
            bf16x8 b0 = *(const bf16x8*)&g_Tswz[((s * 8 + nn) * 64 + lane) * 8];
            bf16x8 b1 = *(const bf16x8*)&g_Tswz[((s * 8 + 4 + nn) * 64 + lane) * 8];
            acc[nn] = __builtin_amdgcn_mfma_f32_16x16x32_bf16(af0, b0, acc[nn], 0, 0, 0);
            acc[nn] = __builtin_amdgcn_mfma_f32_16x16x32_bf16(af1, b1, acc[nn], 0, 0, 0);
        }
        unsigned short* dst = half ? g_Pc : g_Pr;
#pragma unroll
        for (int nn = 0; nn < 4; ++nn)
#pragma unroll
            for (int r = 0; r < 4; ++r) {
                int node = nb + quad * 4 + r;
                if (node < n)
                    dst[node * 128 + li * 64 + nn * 16 + mc] = f2bf(acc[nn][r]);
            }
    }
}

// ---------------------------------------------------------------------------
// L2b: edge masks — wave = 8 edges x 8 lanes x 8 dims; no MFMA, no LDS.
// ---------------------------------------------------------------------------
__global__ __launch_bounds__(256) void edge_mask_kernel(
    const float* __restrict__ tb1, const float* __restrict__ tW2,
    const float* __restrict__ tb2, const float* __restrict__ tnoise,
    const int* __restrict__ row, const int* __restrict__ col,
    float* __restrict__ mask_out, int nE)
{
    int tid = threadIdx.x;
    int lane = tid & 63;
    int sub = lane & 7;
    int eg = lane >> 3;
    int wv = (blockIdx.x * 256 + tid) >> 6;
    int e = wv * 8 + eg;

    float b1_0[8], b1_1[8], w2_0[8], w2_1[8];
    *(float4*)&b1_0[0] = *(const float4*)&tb1[sub * 8];
    *(float4*)&b1_0[4] = *(const float4*)&tb1[sub * 8 + 4];
    *(float4*)&b1_1[0] = *(const float4*)&tb1[64 + sub * 8];
    *(float4*)&b1_1[4] = *(const float4*)&tb1[64 + sub * 8 + 4];
    *(float4*)&w2_0[0] = *(const float4*)&tW2[sub * 8];
    *(float4*)&w2_0[4] = *(const float4*)&tW2[sub * 8 + 4];
    *(float4*)&w2_1[0] = *(const float4*)&tW2[64 + sub * 8];
    *(float4*)&w2_1[4] = *(const float4*)&tW2[64 + sub * 8 + 4];

    int rn = row[e], cn = col[e];
    uint4 qr0 = *(const uint4*)&g_Pr[rn * 128 + sub * 8];
    uint4 qr1 = *(const uint4*)&g_Pr[rn * 128 + 64 + sub * 8];
    uint4 qc0 = *(const uint4*)&g_Pc[cn * 128 + sub * 8];
    uint4 qc1 = *(const uint4*)&g_Pc[cn * 128 + 64 + sub * 8];

    float p0 = 0.f, p1 = 0.f;
    unsigned r0[4] = {qr0.x, qr0.y, qr0.z, qr0.w};
    unsigned r1[4] = {qr1.x, qr1.y, qr1.z, qr1.w};
    unsigned c0[4] = {qc0.x, qc0.y, qc0.z, qc0.w};
    unsigned c1[4] = {qc1.x, qc1.y, qc1.z, qc1.w};
#pragma unroll
    for (int k = 0; k < 4; ++k) {
        float hA = fmaxf(bf2f_lo(r0[k]) + bf2f_lo(c0[k]) + b1_0[2 * k], 0.f);
        float hB = fmaxf(bf2f_hi(r0[k]) + bf2f_hi(c0[k]) + b1_0[2 * k + 1], 0.f);
        p0 = fmaf(hA, w2_0[2 * k], p0);
        p0 = fmaf(hB, w2_0[2 * k + 1], p0);
        float gA = fmaxf(bf2f_lo(r1[k]) + bf2f_lo(c1[k]) + b1_1[2 * k], 0.f);
        float gB = fmaxf(bf2f_hi(r1[k]) + bf2f_hi(c1[k]) + b1_1[2 * k + 1], 0.f);
        p1 = fmaf(gA, w2_1[2 * k], p1);
        p1 = fmaf(gB, w2_1[2 * k + 1], p1);
    }
#pragma unroll
    for (int off = 1; off <= 4; off <<= 1) {
        p0 += __shfl_xor(p0, off, 64);
        p1 += __shfl_xor(p1, off, 64);
    }
    if (sub == 0) {
        float z0 = (tnoise[e] + p0 + tb2[0]) * 2.0f;
        float m0 = 1.0f / (1.0f + expf(-z0));
        g_mt0[e] = m0;
        float z1 = (tnoise[nE + e] + p1 + tb2[1]) * 2.0f;
        float m1 = 1.0f / (1.0f + expf(-z1));
        g_mt1[e] = m1;
        mask_out[e] = m1;
    }
}

// ---------------------------------------------------------------------------
// node-MLP via MFMA: 16 nodes/wave
// ---------------------------------------------------------------------------
__device__ __forceinline__ void nm_body(
    int bid, const unsigned short* __restrict__ cur, int li,
    const float* __restrict__ b1, const float* __restrict__ W2,
    const float* __restrict__ b2, const float* __restrict__ noise,
    float* __restrict__ smout, int n)
{
    int tid = threadIdx.x;
    int wave = tid >> 6, lane = tid & 63;
    int mc = lane & 15, quad = lane >> 4;
    int nb = bid * 64 + wave * 16;
    const unsigned short* basep = cur + (nb + mc) * 64 + quad * 8;
    bf16x8 af0 = *(const bf16x8*)basep;
    bf16x8 af1 = *(const bf16x8*)(basep + 32);
    f32x4 acc[4];
    const f32x4 zero = {0.f, 0.f, 0.f, 0.f};
#pragma unroll
    for (int nn = 0; nn < 4; ++nn) acc[nn] = zero;
#pragma unroll
    for (int nn = 0; nn < 4; ++nn) {
        bf16x8 b0 = *(const bf16x8*)&g_Sswz[((li * 8 + nn) * 64 + lane) * 8];
        bf16x8 b1f = *(const bf16x8*)&g_Sswz[((li * 8 + 4 + nn) * 64 + lane) * 8];
        acc[nn] = __builtin_amdgcn_mfma_f32_16x16x32_bf16(af0, b0, acc[nn], 0, 0, 0);
        acc[nn] = __builtin_amdgcn_mfma_f32_16x16x32_bf16(af1, b1f, acc[nn], 0, 0, 0);
    }
    float p[4];
#pragma unroll
    for (int r = 0; r < 4; ++r) {
        float s = 0.f;
#pragma unroll
        for (int nn = 0; nn < 4; ++nn) {
            float h = acc[nn][r] + b1[nn * 16 + mc];
            s = fmaf(fmaxf(h, 0.f), W2[nn * 16 + mc], s);
        }
        p[r] = s;
    }
#pragma unroll
    for (int off = 8; off >= 1; off >>= 1)
#pragma unroll
        for (int r = 0; r < 4; ++r) p[r] += __shfl_xor(p[r], off, 64);
    if (mc == 0) {
        float b2v = b2[0];
#pragma unroll
        for (int r = 0; r < 4; ++r) {
            int node = nb + quad * 4 + r;
            if (node < n) {
                float z = (noise[node] + p[r] + b2v) * 2.0f;
                smout[node] = 1.0f / (1.0f + expf(-z));
            }
        }
    }
}

__global__ __launch_bounds__(256) void nm0_kernel(
    const float* __restrict__ sb1, const float* __restrict__ sW2,
    const float* __restrict__ sb2, const float* __restrict__ snz, int n)
{
    nm_body(blockIdx.x, g_c1h, 0, sb1, sW2, sb2, snz, g_sm0, n);
}

// ---------------------------------------------------------------------------
// L3: s1 — meta vector-load + shfl broadcast + 16 batched gathers.
// ---------------------------------------------------------------------------
__device__ __forceinline__ void s1_process16(
    int sb, int d2, int myc, float myv, float myvm,
    float& p0, float& p1, float& q0, float& q1)
{
    int cc[16]; float vv[16], mm[16]; unsigned uu[16];
#pragma unroll
    for (int k = 0; k < 16; ++k) {
        cc[k] = __shfl(myc, sb + k, 64);
        vv[k] = __shfl(myv, sb + k, 64);
        mm[k] = __shfl(myvm, sb + k, 64);
    }
#pragma unroll
    for (int k = 0; k < 16; ++k)
        uu[k] = *(const unsigned*)&g_xbf[cc[k] * 64 + 2 * d2];
#pragma unroll
    for (int k = 0; k < 16; ++k) {
        p0 = fmaf(vv[k], bf2f_lo(uu[k]), p0);
        p1 = fmaf(vv[k], bf2f_hi(uu[k]), p1);
        q0 = fmaf(mm[k], bf2f_lo(uu[k]), q0);
        q1 = fmaf(mm[k], bf2f_hi(uu[k]), q1);
    }
}

__global__ __launch_bounds__(256) void s1_kernel(
    const int* __restrict__ colv, const float* __restrict__ vals, int n)
{
    int half = threadIdx.x >> 5;
    int w = blockIdx.x * 8 + half;
    int el = half & 1;
    int d2 = threadIdx.x & 31;
    int sb0 = el << 5;
    int s = g_rowptr[w], e = g_rowptr[w + 1];
    float p0 = 0.f, p1 = 0.f, q0 = 0.f, q1 = 0.f;
    for (int base = s; base < e; base += 32) {
        int rem = e - base;
        int myc = 0; float myv = 0.f, myvm = 0.f;
        if (d2 < rem) {
            myc = colv[base + d2];
            myv = vals[base + d2];
            myvm = myv * g_mt0[base + d2];
        }
        s1_process16(sb0, d2, myc, myv, myvm, p0, p1, q0, q1);
        if (rem > 16)
            s1_process16(sb0 + 16, d2, myc, myv, myvm, p0, p1, q0, q1);
    }
    uint2 pk;
    pk.x = (unsigned)f2bf(p0) | ((unsigned)f2bf(q0) << 16);
    pk.y = (unsigned)f2bf(p1) | ((unsigned)f2bf(q1) << 16);
    *(uint2*)&g_ABh[w * 128 + 4 * d2] = pk;
    *(unsigned*)&g_c1h[w * 64 + 2 * d2] =
        (unsigned)f2bf(p0) | ((unsigned)f2bf(p1) << 16);
}

// ---------------------------------------------------------------------------
// s2 gather block: 8 edges, uint2 gathers
// ---------------------------------------------------------------------------
__device__ __forceinline__ void s2_process8(
    int sb, int d2, int myc, float myv, float myvm,
    float& c0, float& c1, float& t0, float& t1)
{
    int cc[8]; float vv[8], mm[8]; uint2 uu[8];
#pragma unroll
    for (int k = 0; k < 8; ++k) {
        cc[k] = __shfl(myc, sb + k, 64);
        vv[k] = __shfl(myv, sb + k, 64);
        mm[k] = __shfl(myvm, sb + k, 64);
    }
#pragma unroll
    for (int k = 0; k < 8; ++k)
        uu[k] = *(const uint2*)&g_ABh[cc[k] * 128 + 4 * d2];
#pragma unroll
    for (int k = 0; k < 8; ++k) {
        c0 = fmaf(vv[k], bf2f_lo(uu[k].x), c0);
        t0 = fmaf(mm[k], bf2f_hi(uu[k].x), t0);
        c1 = fmaf(vv[k], bf2f_lo(uu[k].y), c1);
        t1 = fmaf(mm[k], bf2f_hi(uu[k].y), t1);
    }
}

// ---------------------------------------------------------------------------
// L6: s2 (emb_t, c2h) || rw0 (g0)
// ---------------------------------------------------------------------------
__device__ __forceinline__ void rw_body(
    int bid, const int* __restrict__ rw_col, const float* __restrict__ rwv,
    const unsigned short* __restrict__ cur, const float* __restrict__ smask,
    unsigned short* __restrict__ outg)
{
    int w = bid * 8 + (threadIdx.x >> 5);
    int d2 = threadIdx.x & 31;
    int base = w * WKLEN;
    float a0 = 0.f, a1 = 0.f;
#pragma unroll
    for (int j = 0; j < WKLEN; ++j) {
        int c = rw_col[base + j];
        float v = rwv[base + j];
        unsigned u = *(const unsigned*)&cur[c * 64 + 2 * d2];
        a0 = fmaf(v, bf2f_lo(u), a0);
        a1 = fmaf(v, bf2f_hi(u), a1);
    }
    float sm = smask[w];
    unsigned u = *(const unsigned*)&cur[w * 64 + 2 * d2];
    float r0 = sm * bf2f_lo(u) + (1.f - sm) * a0;
    float r1 = sm * bf2f_hi(u) + (1.f - sm) * a1;
    *(unsigned*)&outg[w * 64 + 2 * d2] =
        (unsigned)f2bf(r0) | ((unsigned)f2bf(r1) << 16);
}

__global__ __launch_bounds__(256) void s2_rw0_kernel(
    const int* __restrict__ colv, const float* __restrict__ vals,
    const int* __restrict__ rw_col, const float* __restrict__ rwv,
    const float* __restrict__ x, float* __restrict__ emb_t, int n)
{
    if (blockIdx.x >= 6250) {
        rw_body(blockIdx.x - 6250, rw_col, rwv, g_xbf, g_sm0, g_g0h);
        return;
    }
    int half = threadIdx.x >> 5;
    int w = blockIdx.x * 8 + half;
    int el = half & 1;
    int d2 = threadIdx.x & 31;
    int sb0 = el << 5;
    int s = g_rowptr[w], e = g_rowptr[w + 1];
    float c0 = 0.f, c1 = 0.f, t0 = 0.f, t1 = 0.f;
    for (int base = s; base < e; base += 32) {
        int rem = e - base;
        int myc = 0; float myv = 0.f, myvm = 0.f;
        if (d2 < rem) {
            myc = colv[base + d2];
            myv = vals[base + d2];
            myvm = myv * g_mt1[base + d2];
        }
        s2_process8(sb0, d2, myc, myv, myvm, c0, c1, t0, t1);
        if (rem > 8)  s2_process8(sb0 + 8,  d2, myc, myv, myvm, c0, c1, t0, t1);
        if (rem > 16) s2_process8(sb0 + 16, d2, myc, myv, myvm, c0, c1, t0, t1);
        if (rem > 24) s2_process8(sb0 + 24, d2, myc, myv, myvm, c0, c1, t0, t1);
    }
    int o2 = w * 64 + 2 * d2;
    uint2 U2v = *(const uint2*)&g_ABh[w * 128 + 4 * d2];
    float2 et;
    et.x = (x[o2]     + bf2f_hi(U2v.x) + t0) * (1.0f / 3.0f);
    et.y = (x[o2 + 1] + bf2f_hi(U2v.y) + t1) * (1.0f / 3.0f);
    *(float2*)&emb_t[o2] = et;
    *(unsigned*)&g_c2h[o2] = (unsigned)f2bf(c0) | ((unsigned)f2bf(c1) << 16);
}

// ---------------------------------------------------------------------------
// generic spmm body: 16 batched gathers from bf16 h
// ---------------------------------------------------------------------------
__device__ __forceinline__ void sp_process16(
    const unsigned short* __restrict__ h, int sb, int d2,
    int myc, float myv, float& a0, float& a1)
{
    int cc[16]; float vv[16]; unsigned uu[16];
#pragma unroll
    for (int k = 0; k < 16; ++k) {
        cc[k] = __shfl(myc, sb + k, 64);
        vv[k] = __shfl(myv, sb + k, 64);
    }
#pragma unroll
    for (int k = 0; k < 16; ++k)
        uu[k] = *(const unsigned*)&h[cc[k] * 64 + 2 * d2];
#pragma unroll
    for (int k = 0; k < 16; ++k) {
        a0 = fmaf(vv[k], bf2f_lo(uu[k]), a0);
        a1 = fmaf(vv[k], bf2f_hi(uu[k]), a1);
    }
}

__device__ __forceinline__ void spmm_body(
    int bid, const int* __restrict__ colv, const float* __restrict__ vals,
    const unsigned short* __restrict__ h, float* __restrict__ l0,
    float* __restrict__ l1, int* __restrict__ wout, int* __restrict__ d2out)
{
    int half = threadIdx.x >> 5;
    int w = bid * 8 + half;
    int el = half & 1;
    int d2 = threadIdx.x & 31;
    int sb0 = el << 5;
    int s = g_rowptr[w], e = g_rowptr[w + 1];
    float a0 = 0.f, a1 = 0.f;
    for (int base = s; base < e; base += 32) {
        int rem = e - base;
        int myc = 0; float myv = 0.f;
        if (d2 < rem) {
            myc = colv[base + d2];
            myv = vals[base + d2];
        }
        sp_process16(h, sb0, d2, myc, myv, a0, a1);
        if (rem > 16) sp_process16(h, sb0 + 16, d2, myc, myv, a0, a1);
    }
    *l0 = a0; *l1 = a1; *wout = w; *d2out = d2;
}

// ---------------------------------------------------------------------------
// L7: spmm10 (sc1 = A·g0) || nm1 (sm1 from c2h)
// ---------------------------------------------------------------------------
__global__ __launch_bounds__(256) void spmm10_nm1_kernel(
    const int* __restrict__ colv, const float* __restrict__ vals,
    const float* __restrict__ sb1, const float* __restrict__ sW2,
    const float* __restrict__ sb2, const float* __restrict__ snz, int n)
{
    if (blockIdx.x >= 6250) {
        nm_body(blockIdx.x - 6250, g_c2h, 1, sb1, sW2, sb2, snz, g_sm1, n);
        return;
    }
    float a0, a1; int w, d2;
    spmm_body(blockIdx.x, colv, vals, g_g0h, &a0, &a1, &w, &d2);
    *(unsigned*)&g_sc1h[w * 64 + 2 * d2] =
        (unsigned)f2bf(a0) | ((unsigned)f2bf(a1) << 16);
}

// ---------------------------------------------------------------------------
// L8: g1 = rwgate(c1)
// ---------------------------------------------------------------------------
__global__ __launch_bounds__(256) void rw1_kernel(
    const int* __restrict__ rw_col, const float* __restrict__ rwv)
{
    rw_body(blockIdx.x, rw_col, rwv, g_sc1h, g_sm1, g_g0h);
}

// ---------------------------------------------------------------------------
// L9: emb_s = (x + c1 + spmm(vals, g1))/3 — persistent (R1 form, measured
// 59.5us vs 71.8 non-persistent), merged with scalar finalize.
// ---------------------------------------------------------------------------
__global__ __launch_bounds__(256) void spmm12_fin_kernel(
    const int* __restrict__ colv, const float* __restrict__ vals,
    const float* __restrict__ x, float* __restrict__ emb_s,
    float* __restrict__ out, int n)
{
    if (blockIdx.x >= FINGS) {
        __shared__ float red[256];
        float s = 0.f;
        for (int i = threadIdx.x; i < n; i += 256) s += g_sm0[i] + g_sm1[i];
        red[threadIdx.x] = s;
        __syncthreads();
        for (int off = 128; off >= 1; off >>= 1) {
            if (threadIdx.x < off) red[threadIdx.x] += red[threadIdx.x + off];
            __syncthreads();
        }
        if (threadIdx.x == 0) {
            out[6400000] = 0.0f;
            out[6400001] = red[0] / (2.0f * n);
        }
        return;
    }
    for (int vb = blockIdx.x; vb < NGRP; vb += FINGS) {
        float a0, a1; int w, d2;
        spmm_body(vb, colv, vals, g_g0h, &a0, &a1, &w, &d2);
        int o2 = w * 64 + 2 * d2;
        unsigned uc = *(const unsigned*)&g_sc1h[o2];
        float2 es;
        es.x = (x[o2]     + bf2f_lo(uc) + a0) * (1.0f / 3.0f);
        es.y = (x[o2 + 1] + bf2f_hi(uc) + a1) * (1.0f / 3.0f);
        *(float2*)&emb_s[o2] = es;
    }
}

extern "C" void kernel_launch(void* const* d_in, const int* in_sizes, int n_in,
                              void* d_out, int out_size, void* d_ws, size_t ws_size,
                              hipStream_t stream)
{
    const float* x    = (const float*)d_in[0];
    const float* vals = (const float*)d_in[1];
    const float* rwv  = (const float*)d_in[2];
    const float* tW1  = (const float*)d_in[3];
    const float* tb1  = (const float*)d_in[4];
    const float* tW2  = (const float*)d_in[5];
    const float* tb2  = (const float*)d_in[6];
    const float* sW1  = (const float*)d_in[7];
    const float* sb1  = (const float*)d_in[8];
    const float* sW2  = (const float*)d_in[9];
    const float* sb2  = (const float*)d_in[10];
    const float* tnz  = (const float*)d_in[11];
    const float* snz  = (const float*)d_in[12];
    const int* row   = (const int*)d_in[13];
    const int* colv  = (const int*)d_in[14];
    const int* rwcol = (const int*)d_in[16];

    const int n = NNODES;
    const int nE = in_sizes[1];

    float* out   = (float*)d_out;
    float* emb_t = out;
    float* emb_s = out + 3200000;
    float* masko = out + 6400002;

    // L1: misc prep
    misc_kernel<<<1771, 256, 0, stream>>>(x, tW1, sW1, row, n, nE);
    // L2a: P = X @ W1_halves
    prep2_kernel<<<782, 256, 0, stream>>>(n);
    // L2b: edge masks
    edge_mask_kernel<<<nE / 32, 256, 0, stream>>>(tb1, tW2, tb2, tnz,
                                                  row, colv, masko, nE);
    // L3: s1 (cur1|t1 packed + cur1h)
    s1_kernel<<<6250, 256, 0, stream>>>(colv, vals, n);
    // L4: nm0 -> sm0
    nm0_kernel<<<782, 256, 0, stream>>>(sb1, sW2, sb2, snz, n);
    // L5: s2 || rw0
    s2_rw0_kernel<<<12500, 256, 0, stream>>>(colv, vals, rwcol, rwv, x, emb_t, n);
    // L6: spmm10 || nm1
    spmm10_nm1_kernel<<<6250 + 782, 256, 0, stream>>>(colv, vals,
                                                      sb1 + 64, sW2 + 64, sb2 + 1,
                                                      snz + n, n);
    // L7: g1 = rwgate(c1)
    rw1_kernel<<<6250, 256, 0, stream>>>(rwcol, rwv);
    // L8: emb_s + scalars (persistent fin + 1 reduction block)
    spmm12_fin_kernel<<<FINGS + 1, 256, 0, stream>>>(colv, vals, x, emb_s, out, n);
}